// Round 4
// baseline (289.461 us; speedup 1.0000x reference)
//
#include <hip/hip_runtime.h>

#define BB 16
#define NN 8192
#define DMODEL 256
#define DKK 64
#define DVV 64
#define NQQ 256
#define TOK 32
#define MARGIN 0.02f
#define CAP 32768

typedef __attribute__((ext_vector_type(8))) short bf16x8;
typedef __attribute__((ext_vector_type(4))) float f32x4;

// RNE split of f32 into bf16 hi + bf16 lo (x ~= hi + lo, |err| ~ 2^-17 |x|)
__device__ __forceinline__ void split_bf16(float v, unsigned short& h, unsigned short& lo) {
  unsigned u = __float_as_uint(v);
  unsigned hr = (u + 0x7FFFu + ((u >> 16) & 1u)) & 0xFFFF0000u;
  h = (unsigned short)(hr >> 16);
  float r = v - __uint_as_float(hr);
  unsigned ul = __float_as_uint(r);
  lo = (unsigned short)((ul + 0x7FFFu + ((ul >> 16) & 1u)) >> 16);
}

__device__ __forceinline__ unsigned short hi_bf16(float v) {
  unsigned u = __float_as_uint(v);
  return (unsigned short)(((u + 0x7FFFu + ((u >> 16) & 1u)) & 0xFFFF0000u) >> 16);
}

// prep: qk = q @ w_ks (f32, for recheck), split-fragments qhf/qlf, MT = (w_fc @ w_vs)^T
__global__ __launch_bounds__(256) void prep_kernel(
    const float* __restrict__ q, const float* __restrict__ w_ks,
    const float* __restrict__ w_vs, const float* __restrict__ w_fc,
    float* __restrict__ qk, float* __restrict__ MT,
    unsigned short* __restrict__ qhf, unsigned short* __restrict__ qlf) {
  __shared__ float sbuf[DKK];
  const int tid = threadIdx.x;
  const int blk = blockIdx.x;
  if (blk < NQQ) {
    const int s = blk;
    if (tid < DKK) sbuf[tid] = q[s * DKK + tid];
    __syncthreads();
    float acc = 0.f;
#pragma unroll
    for (int k = 0; k < DKK; ++k) acc = fmaf(sbuf[k], w_ks[k * DMODEL + tid], acc);
    qk[s * DMODEL + tid] = acc;
    // B fragment layout: elem idx = ((kstep*16 + stile)*64 + (kg*16 + s15))*8 + jj
    int d = tid;
    int kstep = d >> 5, kg = (d >> 3) & 3, jj = d & 7;
    int stile = s >> 4, s15 = s & 15;
    int e = (((kstep * 16 + stile) * 64) + (kg * 16 + s15)) * 8 + jj;
    unsigned short hb, lb;
    split_bf16(acc, hb, lb);
    qhf[e] = hb; qlf[e] = lb;
  } else {
    const int dm = blk - NQQ;
    if (tid < DVV) sbuf[tid] = w_vs[tid * DMODEL + dm];
    __syncthreads();
    float acc = 0.f;
#pragma unroll
    for (int v = 0; v < DVV; ++v) acc = fmaf(w_fc[tid * DVV + v], sbuf[v], acc);
    MT[dm * DMODEL + tid] = acc;
  }
}

// main: split-bf16 MFMA scores (two-pass LDS), top-2 argmax + margin list,
// one-hot write, scatter S
__global__ __launch_bounds__(256, 8) void score_kernel(
    const float* __restrict__ x, const unsigned short* __restrict__ qhf,
    const unsigned short* __restrict__ qlf,
    float* __restrict__ S, float* __restrict__ hard,
    unsigned* __restrict__ cnt, unsigned* __restrict__ list) {
  __shared__ unsigned short xs[8192];   // [kstep(8)][tile(2)][lane(64)][8] bf16, 16 KB
  __shared__ float rm1[4][TOK];
  __shared__ float rm2[4][TOK];
  __shared__ int   ri1[4][TOK];
  __shared__ int   idx_s[TOK];

  const int tid = threadIdx.x;
  const int w = tid >> 6;       // wave 0..3 -> slot range w*64..w*64+63
  const int l = tid & 63;       // lane
  const int b = blockIdx.y;
  const int n0 = blockIdx.x * TOK;
  const float* xbase = x + ((size_t)b * NN + n0) * DMODEL;
  const float4* xb4 = (const float4*)xbase;

  // staging geometry (each (tok,c4) exactly once across the block)
  const int tok = w * 8 + (l >> 3);
  const int r   = l & 7;
  const int kg  = r >> 1;
  const int j0  = (r & 1) * 4;
  const int ti  = tok >> 4;
  const int t15 = tok & 15;

  // ---- stage pass-1: x-hi fragments ----
#pragma unroll
  for (int it = 0; it < 8; ++it) {
    int c4 = it * 8 + r;
    float4 v = xb4[tok * 64 + c4];
    int e = (((it * 2 + ti) * 64) + (kg * 16 + t15)) * 8 + j0;
    ushort4 hh;
    hh.x = hi_bf16(v.x); hh.y = hi_bf16(v.y);
    hh.z = hi_bf16(v.z); hh.w = hi_bf16(v.w);
    *(ushort4*)(&xs[e]) = hh;
  }
  __syncthreads();

  const bf16x8* bh = (const bf16x8*)qhf;
  const bf16x8* bl = (const bf16x8*)qlf;
  f32x4 acc[2][4];
#pragma unroll
  for (int i = 0; i < 2; ++i)
#pragma unroll
    for (int j = 0; j < 4; ++j) acc[i][j] = (f32x4){0.f, 0.f, 0.f, 0.f};

  // ---- pass 1: Ah*Bh + Ah*Bl ----
#pragma unroll
  for (int k = 0; k < 8; ++k) {
    bf16x8 Ah[2];
#pragma unroll
    for (int i = 0; i < 2; ++i)
      Ah[i] = *(const bf16x8*)(&xs[((k * 2 + i) * 64 + l) * 8]);
#pragma unroll
    for (int j = 0; j < 4; ++j) {
      bf16x8 Bhj = bh[(k * 16 + w * 4 + j) * 64 + l];
      bf16x8 Blj = bl[(k * 16 + w * 4 + j) * 64 + l];
      acc[0][j] = __builtin_amdgcn_mfma_f32_16x16x32_bf16(Ah[0], Bhj, acc[0][j], 0, 0, 0);
      acc[1][j] = __builtin_amdgcn_mfma_f32_16x16x32_bf16(Ah[1], Bhj, acc[1][j], 0, 0, 0);
      acc[0][j] = __builtin_amdgcn_mfma_f32_16x16x32_bf16(Ah[0], Blj, acc[0][j], 0, 0, 0);
      acc[1][j] = __builtin_amdgcn_mfma_f32_16x16x32_bf16(Ah[1], Blj, acc[1][j], 0, 0, 0);
    }
  }
  __syncthreads();

  // ---- restage: x-lo fragments (x tile is L2-hot) ----
#pragma unroll
  for (int it = 0; it < 8; ++it) {
    int c4 = it * 8 + r;
    float4 v = xb4[tok * 64 + c4];
    int e = (((it * 2 + ti) * 64) + (kg * 16 + t15)) * 8 + j0;
    ushort4 ll;
    unsigned short hdum;
    split_bf16(v.x, hdum, ll.x);
    split_bf16(v.y, hdum, ll.y);
    split_bf16(v.z, hdum, ll.z);
    split_bf16(v.w, hdum, ll.w);
    *(ushort4*)(&xs[e]) = ll;
  }
  __syncthreads();

  // ---- pass 2: Al*Bh ----
#pragma unroll
  for (int k = 0; k < 8; ++k) {
    bf16x8 Al[2];
#pragma unroll
    for (int i = 0; i < 2; ++i)
      Al[i] = *(const bf16x8*)(&xs[((k * 2 + i) * 64 + l) * 8]);
#pragma unroll
    for (int j = 0; j < 4; ++j) {
      bf16x8 Bhj = bh[(k * 16 + w * 4 + j) * 64 + l];
      acc[0][j] = __builtin_amdgcn_mfma_f32_16x16x32_bf16(Al[0], Bhj, acc[0][j], 0, 0, 0);
      acc[1][j] = __builtin_amdgcn_mfma_f32_16x16x32_bf16(Al[1], Bhj, acc[1][j], 0, 0, 0);
    }
  }

  // ---- per-token top-2 over this wave's 64 slots ----
  // C/D layout: col(slot) = l&15, row(token) = (l>>4)*4 + reg
  const int s15 = l & 15, g4 = l >> 4;
#pragma unroll
  for (int i = 0; i < 2; ++i) {
#pragma unroll
    for (int rr = 0; rr < 4; ++rr) {
      float m1 = acc[i][0][rr];
      int   i1 = w * 64 + s15;
      float m2 = -1e30f;
#pragma unroll
      for (int j = 1; j < 4; ++j) {
        float v = acc[i][j][rr];
        int   s = w * 64 + j * 16 + s15;
        if (v > m1) { m2 = m1; m1 = v; i1 = s; }
        else if (v > m2) m2 = v;
      }
#pragma unroll
      for (int off = 1; off < 16; off <<= 1) {
        float om1 = __shfl_xor(m1, off, 64);
        int   oi1 = __shfl_xor(i1, off, 64);
        float om2 = __shfl_xor(m2, off, 64);
        if (om1 > m1 || (om1 == m1 && oi1 < i1)) { m2 = fmaxf(m1, om2); m1 = om1; i1 = oi1; }
        else { m2 = fmaxf(m2, om1); }
      }
      if (s15 == 0) {
        int t = i * 16 + g4 * 4 + rr;
        rm1[w][t] = m1; rm2[w][t] = m2; ri1[w][t] = i1;
      }
    }
  }
  __syncthreads();

  // ---- cross-wave merge (waves cover ascending slot ranges -> first-index natural) ----
  if (tid < TOK) {
    float m1 = rm1[0][tid]; int i1 = ri1[0][tid]; float m2 = rm2[0][tid];
#pragma unroll
    for (int ww = 1; ww < 4; ++ww) {
      float om1 = rm1[ww][tid]; int oi1 = ri1[ww][tid]; float om2 = rm2[ww][tid];
      if (om1 > m1) { m2 = fmaxf(m1, om2); m1 = om1; i1 = oi1; }
      else { m2 = fmaxf(m2, om1); }
    }
    idx_s[tid] = i1;
    if (m1 - m2 <= MARGIN) {   // ambiguous under split-bf16 error -> f32 recheck
      unsigned pos = atomicAdd(cnt, 1u);
      if (pos < CAP) list[pos] = (((unsigned)(b * NN + n0 + tid)) << 8) | (unsigned)i1;
    }
  }
  __syncthreads();

  // ---- one-hot write (provisional; recheck patches flagged tokens) ----
  float4* hbase = (float4*)(hard + ((size_t)b * NN + n0) * NQQ);
#pragma unroll
  for (int it = 0; it < 8; ++it) {
    int u = it * 256 + tid;
    int tk = u >> 6;
    int s0 = (u & 63) * 4;
    int tgt = idx_s[tk];
    float4 h;
    h.x = (s0 + 0 == tgt) ? 1.f : 0.f;
    h.y = (s0 + 1 == tgt) ? 1.f : 0.f;
    h.z = (s0 + 2 == tgt) ? 1.f : 0.f;
    h.w = (s0 + 3 == tgt) ? 1.f : 0.f;
    hbase[u] = h;
  }

  // ---- scatter: S[b, idx[t], :] += x[b, n0+t, :] ----
  for (int t = 0; t < TOK; ++t) {
    int tgt = idx_s[t];
    float v = xbase[(size_t)t * DMODEL + tid];
    atomicAdd(&S[((size_t)b * NQQ + tgt) * DMODEL + tid], v);
  }
}

// recheck: exact-f32 scores for ambiguous tokens; patch one-hot + S on flip
__global__ __launch_bounds__(256) void recheck_kernel(
    const float* __restrict__ x, const float* __restrict__ qk,
    const unsigned* __restrict__ cnt, const unsigned* __restrict__ list,
    float* __restrict__ S, float* __restrict__ hard) {
  __shared__ float xrow[DMODEL];
  __shared__ float sv[NQQ];
  __shared__ int   si[NQQ];
  const int tid = threadIdx.x;
  unsigned nc = cnt[0];
  int nA = (int)(nc < (unsigned)CAP ? nc : (unsigned)CAP);
  for (int e = blockIdx.x; e < nA; e += gridDim.x) {
    unsigned pk = list[e];
    int tokid = (int)(pk >> 8);
    int olds  = (int)(pk & 255u);
    const float* xr = x + (size_t)tokid * DMODEL;
    xrow[tid] = xr[tid];
    __syncthreads();
    const float* qr = qk + (size_t)tid * DMODEL;
    float a = 0.f;
#pragma unroll
    for (int d4 = 0; d4 < 64; ++d4) {   // strict sequential-d order (matches exact path)
      float4 qv = *(const float4*)(qr + d4 * 4);
      float4 xv = *(const float4*)(&xrow[d4 * 4]);
      a = fmaf(xv.x, qv.x, a); a = fmaf(xv.y, qv.y, a);
      a = fmaf(xv.z, qv.z, a); a = fmaf(xv.w, qv.w, a);
    }
    sv[tid] = a; si[tid] = tid;
    __syncthreads();
    for (int s = 128; s >= 1; s >>= 1) {
      if (tid < s) {
        float vo = sv[tid + s]; int io = si[tid + s];
        if (vo > sv[tid] || (vo == sv[tid] && io < si[tid])) { sv[tid] = vo; si[tid] = io; }
      }
      __syncthreads();
    }
    int news = si[0];
    if (news != olds) {
      int bb = tokid >> 13;
      if (tid == 0) {
        hard[(size_t)tokid * NQQ + olds] = 0.f;
        hard[(size_t)tokid * NQQ + news] = 1.f;
      }
      float xv = xrow[tid];
      atomicAdd(&S[((size_t)bb * NQQ + olds) * DMODEL + tid], -xv);
      atomicAdd(&S[((size_t)bb * NQQ + news) * DMODEL + tid],  xv);
    }
    __syncthreads();
  }
}

// out[b,s,d] = sum_dm S[b,s,dm] * MT[dm,d]
__global__ __launch_bounds__(256) void out_kernel(
    const float* __restrict__ S, const float* __restrict__ MT,
    float* __restrict__ out) {
  __shared__ float srow[8][DMODEL];
  const int tid = threadIdx.x;
  const int r0 = blockIdx.x * 8;
#pragma unroll
  for (int i = 0; i < 8; ++i) srow[i][tid] = S[(size_t)(r0 + i) * DMODEL + tid];
  __syncthreads();
  float a[8];
#pragma unroll
  for (int i = 0; i < 8; ++i) a[i] = 0.f;
  for (int dm = 0; dm < DMODEL; ++dm) {
    float m = MT[(size_t)dm * DMODEL + tid];
#pragma unroll
    for (int i = 0; i < 8; ++i) a[i] = fmaf(srow[i][dm], m, a[i]);
  }
#pragma unroll
  for (int i = 0; i < 8; ++i) out[(size_t)(r0 + i) * DMODEL + tid] = a[i];
}

extern "C" void kernel_launch(void* const* d_in, const int* in_sizes, int n_in,
                              void* d_out, int out_size, void* d_ws, size_t ws_size,
                              hipStream_t stream) {
  const float* x   = (const float*)d_in[0];
  const float* q   = (const float*)d_in[1];
  const float* wks = (const float*)d_in[2];
  const float* wvs = (const float*)d_in[3];
  const float* wfc = (const float*)d_in[4];

  float* out  = (float*)d_out;                       // (16,256,256)
  float* hard = out + (size_t)BB * NQQ * DMODEL;     // (16,8192,256)

  float* qk = (float*)d_ws;                          // 65536 f
  float* MT = qk + 65536;                            // 65536 f
  float* S  = MT + 65536;                            // 1048576 f (4 MB)
  unsigned* cnt  = (unsigned*)(S + 1048576);         // 64 u32 (pad)
  unsigned* list = cnt + 64;                         // CAP u32
  unsigned short* qhf = (unsigned short*)(list + CAP);  // 65536 bf16
  unsigned short* qlf = qhf + 65536;                    // 65536 bf16

  hipMemsetAsync(S, 0, (size_t)1048576 * sizeof(float), stream);
  hipMemsetAsync(cnt, 0, 256, stream);
  prep_kernel<<<2 * NQQ, 256, 0, stream>>>(q, wks, wvs, wfc, qk, MT, qhf, qlf);
  score_kernel<<<dim3(NN / TOK, BB), 256, 0, stream>>>(x, qhf, qlf, S, hard, cnt, list);
  recheck_kernel<<<2048, 256, 0, stream>>>(x, qk, cnt, list, S, hard);
  out_kernel<<<(BB * NQQ) / 8, 256, 0, stream>>>(S, MT, out);
}